// Round 18
// baseline (4119.813 us; speedup 1.0000x reference)
//
#include <hip/hip_runtime.h>

#define SEQ   512
#define BATCH 64
#define DIN   512
#define DH    512
#define KTOT  1024
#define NWG   128
#define NTH   256

#define RINGD      128                 // ring depth (skew<=2, stale-L2 window)
#define SLAB_BYTES 131072              // 8192 slots x 16 B per step
#define RING_OFF   65536
#define TAGS_BYTES 4096                // memset region (tags use 2 KB)
#define EPMAGIC    0x5A5A0000u
#define RETRY_BOUND 262144u            // bounded: break -> absmax fail, no hang

typedef __attribute__((ext_vector_type(8))) short short8;   // 8 x bf16
typedef __attribute__((ext_vector_type(4))) float f32x4;
typedef __attribute__((ext_vector_type(4))) unsigned int u32x4;   // VGPR quad

__device__ __forceinline__ float tanh_fast(float v) {
    const float e = __expf(2.0f * v);
    return 1.0f - 2.0f / (e + 1.0f);
}
__device__ __forceinline__ unsigned int f2bf(float f) {
    unsigned int u = __float_as_uint(f);
    return (u + 0x7fffu + ((u >> 16) & 1u)) >> 16;
}
__device__ __forceinline__ short8 cvt8(float4 lo, float4 hi) {
    short8 r;
    r[0] = (short)f2bf(lo.x); r[1] = (short)f2bf(lo.y);
    r[2] = (short)f2bf(lo.z); r[3] = (short)f2bf(lo.w);
    r[4] = (short)f2bf(hi.x); r[5] = (short)f2bf(hi.y);
    r[6] = (short)f2bf(hi.z); r[7] = (short)f2bf(hi.w);
    return r;
}
__device__ __forceinline__ unsigned int ld_flag(const unsigned int* p) {
    return __hip_atomic_load(p, __ATOMIC_RELAXED, __HIP_MEMORY_SCOPE_AGENT);
}
__device__ __forceinline__ void st_flag(unsigned int* p, unsigned int v) {
    __hip_atomic_store(p, v, __ATOMIC_RELAXED, __HIP_MEMORY_SCOPE_AGENT);
}
__device__ __forceinline__ unsigned long long ld8_sc1(const void* p) {
    return __hip_atomic_load((const unsigned long long*)p,
                             __ATOMIC_RELAXED, __HIP_MEMORY_SCOPE_AGENT);
}

// Persistent MFMA LSTM, round 18 (= r17 with the asm operand type fixed):
// r16 + DRAIN-FREE publish via epoch-validated 16B slots {h01, ep, h23, ep},
// gated by the packed tags.
// Producer: one sc1 dwordx4 data store, then the 4B tag store with NO
// vmcnt drain (fabric reordering caught by the consumer's epoch check).
// Consumer: poll packed tags (4 lines) -> plain CACHED slot loads (ring of
// 128 steps keeps stale-L2 epochs >=128 off -> can't false-match) -> on
// rare mismatch, bounded sc1 retry sweep. Two static half-phases (k-tiles
// 0-7, 8-15) overlap straggler wait with MFMA. Everything else = r16.
__global__ __launch_bounds__(NTH, 1)
void lstm_mfma(const float* __restrict__ x,
               const float* __restrict__ Wf, const float* __restrict__ bfp,
               const float* __restrict__ Wi, const float* __restrict__ bip,
               const float* __restrict__ Wg, const float* __restrict__ bgp,
               const float* __restrict__ Wo, const float* __restrict__ bop,
               float* __restrict__ out,
               unsigned int* __restrict__ ws_u32)
{
    const int tid = threadIdx.x;
    const int l   = tid & 63;
    const int mt  = tid >> 6;              // wave = M-tile (batches mt*16..+15)
    const int wg  = blockIdx.x;
    const int j0  = wg * 4;

    const int n    = l & 15;               // weight row (gate*4 + jc)
    const int khi  = l >> 4;               // k-group; in C: gate index
    const bool isg = (khi == 2);

    unsigned int* const flags = ws_u32;    // packed: (mt*128 + wg) * 4B
    char* const ring = (char*)ws_u32 + RING_OFF;

    // ---- weights: 32 fragments in VGPRs (r12 mapping) ----------------------
    const float* Wn = (n < 8) ? ((n < 4) ? Wf : Wi) : ((n < 12) ? Wg : Wo);
    const float* wrow = Wn + (size_t)(j0 + (n & 3)) * KTOT + khi * 8;
    short8 Bfr[32];
    #pragma unroll
    for (int kt = 0; kt < 32; ++kt) {
        Bfr[kt] = cvt8(*(const float4*)(wrow + kt * 32),
                       *(const float4*)(wrow + kt * 32 + 4));
    }
    const float* bptr = (khi == 0) ? bfp : (khi == 1) ? bip : (khi == 2) ? bgp : bop;
    const float4 bias4 = *(const float4*)(bptr + j0);

    float cst0 = 0.f, cst1 = 0.f, cst2 = 0.f, cst3 = 0.f;
    float* const hx_out = out + (size_t)SEQ * BATCH * DH;
    float* const cx_out = hx_out + (size_t)BATCH * DH;

    // producer slot: (((mt*16+kth)*64 + (lane_f_base|l))*2 + (wg&1)) * 16
    const int kth         = wg >> 3;
    const int lane_f_base = ((wg & 7) >> 1) << 4;
    const size_t prod_off = ((((size_t)(mt * 16 + kth) * 64)
                              + (size_t)(lane_f_base | l)) * 2
                             + (size_t)(wg & 1)) << 4;

    // packed tag pointers (r16)
    const unsigned int* const f0p = flags + (size_t)mt * 128 + l;
    const unsigned int* const f1p = f0p + 64;
    unsigned int* const my_flag = flags + (size_t)mt * 128 + wg;

    const float* xrow_base = x + (size_t)(mt * 16 + n) * DIN + khi * 8;

    bool dead = false;

    for (int t = 0; t < SEQ && !dead; ++t) {
        f32x4 acc_a = {0.f, 0.f, 0.f, 0.f};
        f32x4 acc_b = {0.f, 0.f, 0.f, 0.f};

        // ---------- phase X: x[t] contribution (dependency-free) -----------
        {
            const float* xr = xrow_base + (size_t)t * BATCH * DIN;
            #pragma unroll
            for (int kt = 0; kt < 16; kt += 2) {
                const short8 a0 = cvt8(*(const float4*)(xr + kt * 32),
                                       *(const float4*)(xr + kt * 32 + 4));
                const short8 a1 = cvt8(*(const float4*)(xr + (kt + 1) * 32),
                                       *(const float4*)(xr + (kt + 1) * 32 + 4));
                acc_a = __builtin_amdgcn_mfma_f32_16x16x32_bf16(Bfr[kt], a0, acc_a, 0, 0, 0);
                acc_b = __builtin_amdgcn_mfma_f32_16x16x32_bf16(Bfr[kt + 1], a1, acc_b, 0, 0, 0);
            }
        }

        if (t > 0) {
            // ------ gate: all 128 same-mt packed tags >= t (r16 poll) ------
            const unsigned int target = (unsigned int)t;
            for (;;) {
                const unsigned int fa = ld_flag(f0p);
                const unsigned int fb = ld_flag(f1p);
                if (__all(fa >= target && fb >= target)) break;
                __builtin_amdgcn_s_sleep(1);
            }
            asm volatile("" ::: "memory");   // keep slot loads after the poll

            const unsigned int e = EPMAGIC | (unsigned int)(t - 1);
            const char* hb = ring + (size_t)((t - 1) & (RINGD - 1)) * SLAB_BYTES
                           + (((size_t)(mt * 16) * 64 + l) << 5);

            #pragma unroll
            for (int hf = 0; hf < 2; ++hf) {
                const char* base = hb + hf * 16384;
                u32x4 sa[8], sb[8];
                // ---- fast path: plain CACHED loads (L2-shared on XCD) -----
                #pragma unroll
                for (int k = 0; k < 8; ++k) {
                    sa[k] = *(const u32x4*)(base + k * 2048);
                    sb[k] = *(const u32x4*)(base + k * 2048 + 16);
                }
                unsigned int bad = 0;
                #pragma unroll
                for (int k = 0; k < 8; ++k) {
                    bad |= (sa[k][1] ^ e) | (sa[k][3] ^ e)
                         | (sb[k][1] ^ e) | (sb[k][3] ^ e);
                }
                if (!__all(bad == 0u)) {
                    // ---- rare path: bounded sc1 retry sweep ---------------
                    for (unsigned int it = 0;; ++it) {
                        #pragma unroll
                        for (int k = 0; k < 8; ++k) {
                            const unsigned long long a0 = ld8_sc1(base + k * 2048);
                            const unsigned long long a1 = ld8_sc1(base + k * 2048 + 8);
                            const unsigned long long b0 = ld8_sc1(base + k * 2048 + 16);
                            const unsigned long long b1 = ld8_sc1(base + k * 2048 + 24);
                            sa[k][0] = (unsigned int)a0; sa[k][1] = (unsigned int)(a0 >> 32);
                            sa[k][2] = (unsigned int)a1; sa[k][3] = (unsigned int)(a1 >> 32);
                            sb[k][0] = (unsigned int)b0; sb[k][1] = (unsigned int)(b0 >> 32);
                            sb[k][2] = (unsigned int)b1; sb[k][3] = (unsigned int)(b1 >> 32);
                        }
                        bad = 0;
                        #pragma unroll
                        for (int k = 0; k < 8; ++k) {
                            bad |= (sa[k][1] ^ e) | (sa[k][3] ^ e)
                                 | (sb[k][1] ^ e) | (sb[k][3] ^ e);
                        }
                        if (__all(bad == 0u)) break;
                        if (it >= RETRY_BOUND) { dead = true; break; }
                        __builtin_amdgcn_s_sleep(1);
                    }
                    if (dead) break;
                }
                // ---- 8 MFMAs for this half --------------------------------
                #pragma unroll
                for (int k = 0; k < 8; ++k) {
                    union { u32x4 u; short8 v; } U;
                    U.u[0] = sa[k][0]; U.u[1] = sa[k][2];
                    U.u[2] = sb[k][0]; U.u[3] = sb[k][2];
                    const int kt = hf * 8 + k;
                    if (kt & 1)
                        acc_b = __builtin_amdgcn_mfma_f32_16x16x32_bf16(Bfr[16 + kt], U.v,
                                                                        acc_b, 0, 0, 0);
                    else
                        acc_a = __builtin_amdgcn_mfma_f32_16x16x32_bf16(Bfr[16 + kt], U.v,
                                                                        acc_a, 0, 0, 0);
                }
            }
            if (dead) break;
        }

        // ---------- epilogue: gates on ALL lanes, gather, update -----------
        float aq0, aq1, aq2, aq3;
        {
            const float m = isg ? 2.0f : 1.0f;
            const float p0 = acc_a[0] + acc_b[0] + bias4.x;
            const float p1 = acc_a[1] + acc_b[1] + bias4.y;
            const float p2 = acc_a[2] + acc_b[2] + bias4.z;
            const float p3 = acc_a[3] + acc_b[3] + bias4.w;
            const float y0 = 1.0f / (1.0f + __expf(-m * p0));
            const float y1 = 1.0f / (1.0f + __expf(-m * p1));
            const float y2 = 1.0f / (1.0f + __expf(-m * p2));
            const float y3 = 1.0f / (1.0f + __expf(-m * p3));
            aq0 = isg ? 2.0f * y0 - 1.0f : y0;
            aq1 = isg ? 2.0f * y1 - 1.0f : y1;
            aq2 = isg ? 2.0f * y2 - 1.0f : y2;
            aq3 = isg ? 2.0f * y3 - 1.0f : y3;
        }
        const float i0 = __shfl_xor(aq0, 16), g0 = __shfl_xor(aq0, 32), o0 = __shfl_xor(aq0, 48);
        const float i1 = __shfl_xor(aq1, 16), g1 = __shfl_xor(aq1, 32), o1 = __shfl_xor(aq1, 48);
        const float i2 = __shfl_xor(aq2, 16), g2 = __shfl_xor(aq2, 32), o2 = __shfl_xor(aq2, 48);
        const float i3 = __shfl_xor(aq3, 16), g3 = __shfl_xor(aq3, 32), o3 = __shfl_xor(aq3, 48);

        const bool active = (l < 16);          // lane l = batch mt*16+l
        float hq0 = 0.f, hq1 = 0.f, hq2 = 0.f, hq3 = 0.f;

        if (active) {
            cst0 = fmaf(aq0, cst0, i0 * g0); hq0 = o0 * tanh_fast(cst0);
            cst1 = fmaf(aq1, cst1, i1 * g1); hq1 = o1 * tanh_fast(cst1);
            cst2 = fmaf(aq2, cst2, i2 * g2); hq2 = o2 * tanh_fast(cst2);
            cst3 = fmaf(aq3, cst3, i3 * g3); hq3 = o3 * tanh_fast(cst3);

            if (t < SEQ - 1) {
                // self-certifying 16B slot: {h01, ep, h23, ep}, sc1 store
                u32x4 pkt;
                pkt[0] = f2bf(hq0) | (f2bf(hq1) << 16);
                pkt[1] = EPMAGIC | (unsigned int)t;
                pkt[2] = f2bf(hq2) | (f2bf(hq3) << 16);
                pkt[3] = EPMAGIC | (unsigned int)t;
                char* hp_w = ring + (size_t)(t & (RINGD - 1)) * SLAB_BYTES + prod_off;
                asm volatile("global_store_dwordx4 %0, %1, off sc0 sc1"
                             :: "v"(hp_w), "v"(pkt) : "memory");
            }
        }

        if (t < SEQ - 1) {
            // NO vmcnt drain — tag follows data in issue order; epoch check
            // on the consumer side covers any fabric completion reordering.
            if (l == 0) st_flag(my_flag, (unsigned int)(t + 1));
        }

        if (active) {      // out writes off the critical path
            const int b = mt * 16 + l;
            const float4 ov = make_float4(hq0, hq1, hq2, hq3);
            *(float4*)(out + ((size_t)t * BATCH + b) * DH + j0) = ov;
            if (t == SEQ - 1) {
                *(float4*)(hx_out + (size_t)b * DH + j0) = ov;
                *(float4*)(cx_out + (size_t)b * DH + j0) =
                    make_float4(cst0, cst1, cst2, cst3);
            }
        }
    }
}

extern "C" void kernel_launch(void* const* d_in, const int* in_sizes, int n_in,
                              void* d_out, int out_size, void* d_ws, size_t ws_size,
                              hipStream_t stream)
{
    const float* x  = (const float*)d_in[0];
    const float* Wf = (const float*)d_in[1];
    const float* bf = (const float*)d_in[2];
    const float* Wi = (const float*)d_in[3];
    const float* bi = (const float*)d_in[4];
    const float* Wg = (const float*)d_in[5];
    const float* bg = (const float*)d_in[6];
    const float* Wo = (const float*)d_in[7];
    const float* bo = (const float*)d_in[8];
    float* out = (float*)d_out;

    // Zero the packed tags every call (monotone within a call; ws poisoned
    // 0xAA once, never re-poisoned). Ring slots are self-certifying: stale
    // epochs differ by >=128 (same call) or carry other-t values (previous
    // call / replay) and can never match the expected magic|(t-1).
    (void)hipMemsetAsync(d_ws, 0, TAGS_BYTES, stream);

    lstm_mfma<<<NWG, NTH, 0, stream>>>(x, Wf, bf, Wi, bi, Wg, bg, Wo, bo,
                                       out, (unsigned int*)d_ws);
}

// Round 19
// 3903.489 us; speedup vs baseline: 1.0554x; 1.0554x over previous
//
#include <hip/hip_runtime.h>

#define SEQ   512
#define BATCH 64
#define DIN   512
#define DH    512
#define KTOT  1024
#define NWG   128
#define NTH   256

#define RINGD      128                 // ring depth (skew<=2; wrap self-heals)
#define SLAB_BYTES 131072              // 8192 slots x 16 B per step
#define EPMAGIC    0x5A5A0000u
#define RETRY_BOUND 65536u             // bounded: break -> absmax fail, no hang

typedef __attribute__((ext_vector_type(8))) short short8;   // 8 x bf16
typedef __attribute__((ext_vector_type(4))) float f32x4;
typedef __attribute__((ext_vector_type(4))) unsigned int u32x4;   // VGPR quad

__device__ __forceinline__ float tanh_fast(float v) {
    const float e = __expf(2.0f * v);
    return 1.0f - 2.0f / (e + 1.0f);
}
__device__ __forceinline__ unsigned int f2bf(float f) {
    unsigned int u = __float_as_uint(f);
    return (u + 0x7fffu + ((u >> 16) & 1u)) >> 16;
}
__device__ __forceinline__ short8 cvt8(float4 lo, float4 hi) {
    short8 r;
    r[0] = (short)f2bf(lo.x); r[1] = (short)f2bf(lo.y);
    r[2] = (short)f2bf(lo.z); r[3] = (short)f2bf(lo.w);
    r[4] = (short)f2bf(hi.x); r[5] = (short)f2bf(hi.y);
    r[6] = (short)f2bf(hi.z); r[7] = (short)f2bf(hi.w);
    return r;
}
__device__ __forceinline__ unsigned long long ld8_sc1(const void* p) {
    return __hip_atomic_load((const unsigned long long*)p,
                             __ATOMIC_RELAXED, __HIP_MEMORY_SCOPE_AGENT);
}

// Persistent MFMA LSTM, round 19: TAGLESS epoch-certified exchange.
// Producer: gates -> ONE sc1 dwordx4 slot store {h01, ep, h23, ep}. No
// drain, no tag, no flags, no ws memset. The slot IS the publish.
// Consumer: speculative CACHED slot loads (virgin ring slab -> L2-shared
// across the XCD's 16 WGs, r8 win) -> epoch check -> on mismatch, bounded
// sc1 retry with sleep (the retry IS the wait; downside bounded ~= r16's
// post-poll load). Two static half-phases. Compute path = r16/r12.
__global__ __launch_bounds__(NTH, 1)
void lstm_mfma(const float* __restrict__ x,
               const float* __restrict__ Wf, const float* __restrict__ bfp,
               const float* __restrict__ Wi, const float* __restrict__ bip,
               const float* __restrict__ Wg, const float* __restrict__ bgp,
               const float* __restrict__ Wo, const float* __restrict__ bop,
               float* __restrict__ out,
               char* __restrict__ ring)
{
    const int tid = threadIdx.x;
    const int l   = tid & 63;
    const int mt  = tid >> 6;              // wave = M-tile (batches mt*16..+15)
    const int wg  = blockIdx.x;
    const int j0  = wg * 4;

    const int n    = l & 15;               // weight row (gate*4 + jc)
    const int khi  = l >> 4;               // k-group; in C: gate index
    const bool isg = (khi == 2);

    // ---- weights: 32 fragments in VGPRs (r12 mapping) ----------------------
    const float* Wn = (n < 8) ? ((n < 4) ? Wf : Wi) : ((n < 12) ? Wg : Wo);
    const float* wrow = Wn + (size_t)(j0 + (n & 3)) * KTOT + khi * 8;
    short8 Bfr[32];
    #pragma unroll
    for (int kt = 0; kt < 32; ++kt) {
        Bfr[kt] = cvt8(*(const float4*)(wrow + kt * 32),
                       *(const float4*)(wrow + kt * 32 + 4));
    }
    const float* bptr = (khi == 0) ? bfp : (khi == 1) ? bip : (khi == 2) ? bgp : bop;
    const float4 bias4 = *(const float4*)(bptr + j0);

    float cst0 = 0.f, cst1 = 0.f, cst2 = 0.f, cst3 = 0.f;
    float* const hx_out = out + (size_t)SEQ * BATCH * DH;
    float* const cx_out = hx_out + (size_t)BATCH * DH;

    // producer slot: (((mt*16+kth)*64 + (lane_f_base|l))*2 + (wg&1)) * 16
    const int kth         = wg >> 3;
    const int lane_f_base = ((wg & 7) >> 1) << 4;
    const size_t prod_off = ((((size_t)(mt * 16 + kth) * 64)
                              + (size_t)(lane_f_base | l)) * 2
                             + (size_t)(wg & 1)) << 4;

    const float* xrow_base = x + (size_t)(mt * 16 + n) * DIN + khi * 8;

    bool dead = false;

    for (int t = 0; t < SEQ && !dead; ++t) {
        f32x4 acc_a = {0.f, 0.f, 0.f, 0.f};
        f32x4 acc_b = {0.f, 0.f, 0.f, 0.f};

        // ---------- phase X: x[t] contribution (dependency-free) -----------
        {
            const float* xr = xrow_base + (size_t)t * BATCH * DIN;
            #pragma unroll
            for (int kt = 0; kt < 16; kt += 2) {
                const short8 a0 = cvt8(*(const float4*)(xr + kt * 32),
                                       *(const float4*)(xr + kt * 32 + 4));
                const short8 a1 = cvt8(*(const float4*)(xr + (kt + 1) * 32),
                                       *(const float4*)(xr + (kt + 1) * 32 + 4));
                acc_a = __builtin_amdgcn_mfma_f32_16x16x32_bf16(Bfr[kt], a0, acc_a, 0, 0, 0);
                acc_b = __builtin_amdgcn_mfma_f32_16x16x32_bf16(Bfr[kt + 1], a1, acc_b, 0, 0, 0);
            }
        }

        if (t > 0) {
            const unsigned int e = EPMAGIC | (unsigned int)(t - 1);
            const char* hb = ring + (size_t)((t - 1) & (RINGD - 1)) * SLAB_BYTES
                           + (((size_t)(mt * 16) * 64 + l) << 5);

            #pragma unroll
            for (int hf = 0; hf < 2; ++hf) {
                const char* base = hb + hf * 16384;
                u32x4 sa[8], sb[8];
                // ---- speculative fast path: plain CACHED loads ------------
                #pragma unroll
                for (int k = 0; k < 8; ++k) {
                    sa[k] = *(const u32x4*)(base + k * 2048);
                    sb[k] = *(const u32x4*)(base + k * 2048 + 16);
                }
                unsigned int bad = 0;
                #pragma unroll
                for (int k = 0; k < 8; ++k) {
                    bad |= (sa[k][1] ^ e) | (sa[k][3] ^ e)
                         | (sb[k][1] ^ e) | (sb[k][3] ^ e);
                }
                if (!__all(bad == 0u)) {
                    // ---- wait path: bounded sc1 retry sweep ---------------
                    for (unsigned int it = 0;; ++it) {
                        #pragma unroll
                        for (int k = 0; k < 8; ++k) {
                            const unsigned long long a0 = ld8_sc1(base + k * 2048);
                            const unsigned long long a1 = ld8_sc1(base + k * 2048 + 8);
                            const unsigned long long b0 = ld8_sc1(base + k * 2048 + 16);
                            const unsigned long long b1 = ld8_sc1(base + k * 2048 + 24);
                            sa[k][0] = (unsigned int)a0; sa[k][1] = (unsigned int)(a0 >> 32);
                            sa[k][2] = (unsigned int)a1; sa[k][3] = (unsigned int)(a1 >> 32);
                            sb[k][0] = (unsigned int)b0; sb[k][1] = (unsigned int)(b0 >> 32);
                            sb[k][2] = (unsigned int)b1; sb[k][3] = (unsigned int)(b1 >> 32);
                        }
                        bad = 0;
                        #pragma unroll
                        for (int k = 0; k < 8; ++k) {
                            bad |= (sa[k][1] ^ e) | (sa[k][3] ^ e)
                                 | (sb[k][1] ^ e) | (sb[k][3] ^ e);
                        }
                        if (__all(bad == 0u)) break;
                        if (it >= RETRY_BOUND) { dead = true; break; }
                        __builtin_amdgcn_s_sleep(4);
                    }
                    if (dead) break;
                }
                // ---- 8 MFMAs for this half --------------------------------
                #pragma unroll
                for (int k = 0; k < 8; ++k) {
                    union { u32x4 u; short8 v; } U;
                    U.u[0] = sa[k][0]; U.u[1] = sa[k][2];
                    U.u[2] = sb[k][0]; U.u[3] = sb[k][2];
                    const int kt = hf * 8 + k;
                    if (kt & 1)
                        acc_b = __builtin_amdgcn_mfma_f32_16x16x32_bf16(Bfr[16 + kt], U.v,
                                                                        acc_b, 0, 0, 0);
                    else
                        acc_a = __builtin_amdgcn_mfma_f32_16x16x32_bf16(Bfr[16 + kt], U.v,
                                                                        acc_a, 0, 0, 0);
                }
            }
            if (dead) break;
        }

        // ---------- epilogue: gates on ALL lanes, gather, update -----------
        float aq0, aq1, aq2, aq3;
        {
            const float m = isg ? 2.0f : 1.0f;
            const float p0 = acc_a[0] + acc_b[0] + bias4.x;
            const float p1 = acc_a[1] + acc_b[1] + bias4.y;
            const float p2 = acc_a[2] + acc_b[2] + bias4.z;
            const float p3 = acc_a[3] + acc_b[3] + bias4.w;
            const float y0 = 1.0f / (1.0f + __expf(-m * p0));
            const float y1 = 1.0f / (1.0f + __expf(-m * p1));
            const float y2 = 1.0f / (1.0f + __expf(-m * p2));
            const float y3 = 1.0f / (1.0f + __expf(-m * p3));
            aq0 = isg ? 2.0f * y0 - 1.0f : y0;
            aq1 = isg ? 2.0f * y1 - 1.0f : y1;
            aq2 = isg ? 2.0f * y2 - 1.0f : y2;
            aq3 = isg ? 2.0f * y3 - 1.0f : y3;
        }
        const float i0 = __shfl_xor(aq0, 16), g0 = __shfl_xor(aq0, 32), o0 = __shfl_xor(aq0, 48);
        const float i1 = __shfl_xor(aq1, 16), g1 = __shfl_xor(aq1, 32), o1 = __shfl_xor(aq1, 48);
        const float i2 = __shfl_xor(aq2, 16), g2 = __shfl_xor(aq2, 32), o2 = __shfl_xor(aq2, 48);
        const float i3 = __shfl_xor(aq3, 16), g3 = __shfl_xor(aq3, 32), o3 = __shfl_xor(aq3, 48);

        const bool active = (l < 16);          // lane l = batch mt*16+l
        float hq0 = 0.f, hq1 = 0.f, hq2 = 0.f, hq3 = 0.f;

        if (active) {
            cst0 = fmaf(aq0, cst0, i0 * g0); hq0 = o0 * tanh_fast(cst0);
            cst1 = fmaf(aq1, cst1, i1 * g1); hq1 = o1 * tanh_fast(cst1);
            cst2 = fmaf(aq2, cst2, i2 * g2); hq2 = o2 * tanh_fast(cst2);
            cst3 = fmaf(aq3, cst3, i3 * g3); hq3 = o3 * tanh_fast(cst3);

            if (t < SEQ - 1) {
                // publish: ONE self-certifying 16B sc1 store. No drain/tag.
                u32x4 pkt;
                pkt[0] = f2bf(hq0) | (f2bf(hq1) << 16);
                pkt[1] = EPMAGIC | (unsigned int)t;
                pkt[2] = f2bf(hq2) | (f2bf(hq3) << 16);
                pkt[3] = EPMAGIC | (unsigned int)t;
                char* hp_w = ring + (size_t)(t & (RINGD - 1)) * SLAB_BYTES + prod_off;
                asm volatile("global_store_dwordx4 %0, %1, off sc0 sc1"
                             :: "v"(hp_w), "v"(pkt) : "memory");
            }

            // out writes off the critical path
            const int b = mt * 16 + l;
            const float4 ov = make_float4(hq0, hq1, hq2, hq3);
            *(float4*)(out + ((size_t)t * BATCH + b) * DH + j0) = ov;
            if (t == SEQ - 1) {
                *(float4*)(hx_out + (size_t)b * DH + j0) = ov;
                *(float4*)(cx_out + (size_t)b * DH + j0) =
                    make_float4(cst0, cst1, cst2, cst3);
            }
        }
    }
}

extern "C" void kernel_launch(void* const* d_in, const int* in_sizes, int n_in,
                              void* d_out, int out_size, void* d_ws, size_t ws_size,
                              hipStream_t stream)
{
    const float* x  = (const float*)d_in[0];
    const float* Wf = (const float*)d_in[1];
    const float* bf = (const float*)d_in[2];
    const float* Wi = (const float*)d_in[3];
    const float* bi = (const float*)d_in[4];
    const float* Wg = (const float*)d_in[5];
    const float* bg = (const float*)d_in[6];
    const float* Wo = (const float*)d_in[7];
    const float* bo = (const float*)d_in[8];
    float* out = (float*)d_out;

    // NO ws init: ring slots are self-certifying. 0xAA poison, previous-call
    // values (epoch differs by multiples of 128 mod ring), and replay values
    // (byte-identical, deterministic) all either mismatch -> wait, or match
    // with identical data.
    lstm_mfma<<<NWG, NTH, 0, stream>>>(x, Wf, bf, Wi, bi, Wg, bg, Wo, bo,
                                       out, (char*)d_ws);
}

// Round 20
// 3217.231 us; speedup vs baseline: 1.2805x; 1.2133x over previous
//
#include <hip/hip_runtime.h>

#define SEQ   512
#define BATCH 64
#define DIN   512
#define DH    512
#define KTOT  1024
#define NWG   128
#define NTH   256
#define HBUF_BYTES 65536   // one h step: 4 mt * 128 wg * 128 B

// ws layout (bytes):
//   [0, 2K)     packed per-(mt,wg) tags: (mt*128 + wg) * 4B
//   [64K, ...)  per-step virgin h buffers (511 x 64 KB), layout [mt][wg][l]*8B
#define FLAGS_BYTES 65536
#define HBASE_OFF   65536

typedef __attribute__((ext_vector_type(8))) short short8;   // 8 x bf16
typedef __attribute__((ext_vector_type(4))) float f32x4;
typedef __attribute__((ext_vector_type(4))) unsigned int u32x4;

__device__ __forceinline__ float tanh_fast(float v) {
    const float e = __expf(2.0f * v);
    return 1.0f - 2.0f / (e + 1.0f);
}
__device__ __forceinline__ unsigned int f2bf(float f) {
    unsigned int u = __float_as_uint(f);
    return (u + 0x7fffu + ((u >> 16) & 1u)) >> 16;
}
__device__ __forceinline__ short8 cvt8(float4 lo, float4 hi) {
    short8 r;
    r[0] = (short)f2bf(lo.x); r[1] = (short)f2bf(lo.y);
    r[2] = (short)f2bf(lo.z); r[3] = (short)f2bf(lo.w);
    r[4] = (short)f2bf(hi.x); r[5] = (short)f2bf(hi.y);
    r[6] = (short)f2bf(hi.z); r[7] = (short)f2bf(hi.w);
    return r;
}
__device__ __forceinline__ unsigned long long ld_flag64(const unsigned long long* p) {
    return __hip_atomic_load(p, __ATOMIC_RELAXED, __HIP_MEMORY_SCOPE_AGENT);
}
__device__ __forceinline__ void st_flag(unsigned int* p, unsigned int v) {
    __hip_atomic_store(p, v, __ATOMIC_RELAXED, __HIP_MEMORY_SCOPE_AGENT);
}
__device__ __forceinline__ void st_h(unsigned long long* p, unsigned long long v) {
    __hip_atomic_store(p, v, __ATOMIC_RELAXED, __HIP_MEMORY_SCOPE_AGENT);
}

// Persistent MFMA LSTM, round 20: r16 + COALESCED publish.
// Slab layout [mt][wg][lane]*8B: a producer wave's 16 active lanes store a
// CONTIGUOUS 128B block (1-2 fabric transactions vs r16's 16 scattered 8B
// at 32B stride) -> shorter drain ack, 8x fewer fabric ops, tighter jitter.
// Consumer: per k-tile, two 8B cached loads (producers p0 = kt*8+khi*2 and
// p0+1) from the virgin per-step buffer (L2-shared on XCD, r8 win).
// Poll: ONE u64 load/lane covers tags 2l, 2l+1 (128 tags, 4 lines).
// Everything else identical to r16 (barrier-free per-wave tags, drain+tag
// order, operand-swapped MFMA, all-lane gates).
__global__ __launch_bounds__(NTH, 1)
void lstm_mfma(const float* __restrict__ x,
               const float* __restrict__ Wf, const float* __restrict__ bfp,
               const float* __restrict__ Wi, const float* __restrict__ bip,
               const float* __restrict__ Wg, const float* __restrict__ bgp,
               const float* __restrict__ Wo, const float* __restrict__ bop,
               float* __restrict__ out,
               unsigned int* __restrict__ ws_u32)
{
    const int tid = threadIdx.x;
    const int l   = tid & 63;
    const int mt  = tid >> 6;              // wave = M-tile (batches mt*16..+15)
    const int wg  = blockIdx.x;
    const int j0  = wg * 4;

    const int n    = l & 15;               // weight row (gate*4 + jc); bslot
    const int khi  = l >> 4;               // k-group; in C: gate index
    const bool isg = (khi == 2);

    unsigned int* const flags = ws_u32;    // packed: (mt*128 + wg) * 4B
    char* const hbase = (char*)ws_u32 + HBASE_OFF;

    // ---- weights: 32 fragments in VGPRs (r12 mapping) ----------------------
    const float* Wn = (n < 8) ? ((n < 4) ? Wf : Wi) : ((n < 12) ? Wg : Wo);
    const float* wrow = Wn + (size_t)(j0 + (n & 3)) * KTOT + khi * 8;
    short8 Bfr[32];
    #pragma unroll
    for (int kt = 0; kt < 32; ++kt) {
        Bfr[kt] = cvt8(*(const float4*)(wrow + kt * 32),
                       *(const float4*)(wrow + kt * 32 + 4));
    }
    const float* bptr = (khi == 0) ? bfp : (khi == 1) ? bip : (khi == 2) ? bgp : bop;
    const float4 bias4 = *(const float4*)(bptr + j0);

    float cst0 = 0.f, cst1 = 0.f, cst2 = 0.f, cst3 = 0.f;
    float* const hx_out = out + (size_t)SEQ * BATCH * DH;
    float* const cx_out = hx_out + (size_t)BATCH * DH;

    // producer base: contiguous 128B block for this (mt, wg)
    const size_t prod_base = ((size_t)(mt * 128 + wg)) << 7;   // *128

    // poll: one u64 per lane covers tags 2l, 2l+1 of this mt-group
    const unsigned long long* const fpair =
        (const unsigned long long*)(flags + (size_t)mt * 128) + l;
    unsigned int* const my_flag = flags + (size_t)mt * 128 + wg;

    const float* xrow_base = x + (size_t)(mt * 16 + n) * DIN + khi * 8;

    for (int t = 0; t < SEQ; ++t) {
        f32x4 acc_a = {0.f, 0.f, 0.f, 0.f};
        f32x4 acc_b = {0.f, 0.f, 0.f, 0.f};

        // ---------- phase X: x[t] contribution (dependency-free) -----------
        {
            const float* xr = xrow_base + (size_t)t * BATCH * DIN;
            #pragma unroll
            for (int kt = 0; kt < 16; kt += 2) {
                const short8 a0 = cvt8(*(const float4*)(xr + kt * 32),
                                       *(const float4*)(xr + kt * 32 + 4));
                const short8 a1 = cvt8(*(const float4*)(xr + (kt + 1) * 32),
                                       *(const float4*)(xr + (kt + 1) * 32 + 4));
                acc_a = __builtin_amdgcn_mfma_f32_16x16x32_bf16(Bfr[kt], a0, acc_a, 0, 0, 0);
                acc_b = __builtin_amdgcn_mfma_f32_16x16x32_bf16(Bfr[kt + 1], a1, acc_b, 0, 0, 0);
            }
        }

        if (t > 0) {
            // ------ per-wave dependency wait: 128 same-mt tags >= t --------
            const unsigned int target = (unsigned int)t;
            for (;;) {
                const unsigned long long fp = ld_flag64(fpair);
                const unsigned int fa = (unsigned int)fp;
                const unsigned int fb = (unsigned int)(fp >> 32);
                if (__all(fa >= target && fb >= target)) break;
                __builtin_amdgcn_s_sleep(1);
            }
            asm volatile("" ::: "memory");   // keep h-loads after the poll

            // ---------- phase H: h[t-1], virgin buffer, cached loads -------
            // k-tile kt: producers p0 = kt*8 + khi*2 (cols e0..3), p0+1 (e4..7);
            // this lane's batch slot = n. Layout [mt][wg][l]*8B.
            const char* hb = hbase + (size_t)(t - 1) * HBUF_BYTES
                           + ((size_t)(mt * 128) << 7)
                           + ((size_t)khi << 8)            // khi*2 producers *128
                           + ((size_t)n << 3);             // bslot*8
            unsigned long long q0[16], q1[16];
            #pragma unroll
            for (int kt = 0; kt < 16; ++kt) {
                const char* pc = hb + ((size_t)kt << 10);  // kt*8 producers *128
                q0[kt] = *(const unsigned long long*)pc;
                q1[kt] = *(const unsigned long long*)(pc + 128);
            }
            #pragma unroll
            for (int kt = 0; kt < 16; kt += 2) {
                union { u32x4 u; short8 v; } U0, U1;
                U0.u[0] = (unsigned int)q0[kt];
                U0.u[1] = (unsigned int)(q0[kt] >> 32);
                U0.u[2] = (unsigned int)q1[kt];
                U0.u[3] = (unsigned int)(q1[kt] >> 32);
                U1.u[0] = (unsigned int)q0[kt + 1];
                U1.u[1] = (unsigned int)(q0[kt + 1] >> 32);
                U1.u[2] = (unsigned int)q1[kt + 1];
                U1.u[3] = (unsigned int)(q1[kt + 1] >> 32);
                acc_a = __builtin_amdgcn_mfma_f32_16x16x32_bf16(Bfr[16 + kt], U0.v,
                                                                acc_a, 0, 0, 0);
                acc_b = __builtin_amdgcn_mfma_f32_16x16x32_bf16(Bfr[17 + kt], U1.v,
                                                                acc_b, 0, 0, 0);
            }
        }

        // ---------- epilogue: gates on ALL lanes, gather, update -----------
        float aq0, aq1, aq2, aq3;
        {
            const float m = isg ? 2.0f : 1.0f;
            const float p0 = acc_a[0] + acc_b[0] + bias4.x;
            const float p1 = acc_a[1] + acc_b[1] + bias4.y;
            const float p2 = acc_a[2] + acc_b[2] + bias4.z;
            const float p3 = acc_a[3] + acc_b[3] + bias4.w;
            const float y0 = 1.0f / (1.0f + __expf(-m * p0));
            const float y1 = 1.0f / (1.0f + __expf(-m * p1));
            const float y2 = 1.0f / (1.0f + __expf(-m * p2));
            const float y3 = 1.0f / (1.0f + __expf(-m * p3));
            aq0 = isg ? 2.0f * y0 - 1.0f : y0;
            aq1 = isg ? 2.0f * y1 - 1.0f : y1;
            aq2 = isg ? 2.0f * y2 - 1.0f : y2;
            aq3 = isg ? 2.0f * y3 - 1.0f : y3;
        }
        const float i0 = __shfl_xor(aq0, 16), g0 = __shfl_xor(aq0, 32), o0 = __shfl_xor(aq0, 48);
        const float i1 = __shfl_xor(aq1, 16), g1 = __shfl_xor(aq1, 32), o1 = __shfl_xor(aq1, 48);
        const float i2 = __shfl_xor(aq2, 16), g2 = __shfl_xor(aq2, 32), o2 = __shfl_xor(aq2, 48);
        const float i3 = __shfl_xor(aq3, 16), g3 = __shfl_xor(aq3, 32), o3 = __shfl_xor(aq3, 48);

        const bool active = (l < 16);          // lane l = batch mt*16+l
        float hq0 = 0.f, hq1 = 0.f, hq2 = 0.f, hq3 = 0.f;

        if (active) {
            cst0 = fmaf(aq0, cst0, i0 * g0); hq0 = o0 * tanh_fast(cst0);
            cst1 = fmaf(aq1, cst1, i1 * g1); hq1 = o1 * tanh_fast(cst1);
            cst2 = fmaf(aq2, cst2, i2 * g2); hq2 = o2 * tanh_fast(cst2);
            cst3 = fmaf(aq3, cst3, i3 * g3); hq3 = o3 * tanh_fast(cst3);

            if (t < SEQ - 1) {
                // COALESCED publish: lanes 0..15 store contiguous 128B
                const unsigned long long pk =
                    (unsigned long long)(f2bf(hq0) | (f2bf(hq1) << 16))
                    | ((unsigned long long)(f2bf(hq2) | (f2bf(hq3) << 16)) << 32);
                unsigned long long* hp_w = (unsigned long long*)
                    (hbase + (size_t)t * HBUF_BYTES + prod_base + ((size_t)l << 3));
                st_h(hp_w, pk);     // sc1 write-through: visible at IF$
            }
        }

        if (t < SEQ - 1) {
            // this wave's h-stores drained, then publish this wave's tag
            asm volatile("s_waitcnt vmcnt(0)" ::: "memory");
            if (l == 0) st_flag(my_flag, (unsigned int)(t + 1));
        }

        if (active) {      // out writes off the critical path
            const int b = mt * 16 + l;
            const float4 ov = make_float4(hq0, hq1, hq2, hq3);
            *(float4*)(out + ((size_t)t * BATCH + b) * DH + j0) = ov;
            if (t == SEQ - 1) {
                *(float4*)(hx_out + (size_t)b * DH + j0) = ov;
                *(float4*)(cx_out + (size_t)b * DH + j0) =
                    make_float4(cst0, cst1, cst2, cst3);
            }
        }
    }
}

extern "C" void kernel_launch(void* const* d_in, const int* in_sizes, int n_in,
                              void* d_out, int out_size, void* d_ws, size_t ws_size,
                              hipStream_t stream)
{
    const float* x  = (const float*)d_in[0];
    const float* Wf = (const float*)d_in[1];
    const float* bf = (const float*)d_in[2];
    const float* Wi = (const float*)d_in[3];
    const float* bi = (const float*)d_in[4];
    const float* Wg = (const float*)d_in[5];
    const float* bg = (const float*)d_in[6];
    const float* Wo = (const float*)d_in[7];
    const float* bo = (const float*)d_in[8];
    float* out = (float*)d_out;

    // Tags must be 0 every call (monotone within a call; ws poisoned 0xAA
    // once, never re-poisoned). h buffers: virgin per step, written before
    // read (tag-gated); across graph replays values are byte-identical.
    (void)hipMemsetAsync(d_ws, 0, FLAGS_BYTES, stream);

    lstm_mfma<<<NWG, NTH, 0, stream>>>(x, Wf, bf, Wi, bi, Wg, bg, Wo, bo,
                                       out, (unsigned int*)d_ws);
}

// Round 21
// 3090.850 us; speedup vs baseline: 1.3329x; 1.0409x over previous
//
#include <hip/hip_runtime.h>

#define SEQ   512
#define BATCH 64
#define DIN   512
#define DH    512
#define KTOT  1024
#define NWG   128
#define NTH   256
#define HBUF_BYTES 65536   // one h step: 64 tiles * 64 lanes * 16 B

// ws layout (bytes):
//   [0, 2K)     PACKED per-(mt,wg) tags: (mt*128 + wg) * 4B (4 lines/poll)
//   [64K, ...)  per-step virgin h buffers (511 x 64 KB)
#define FLAGS_BYTES 65536
#define HBASE_OFF   65536

typedef __attribute__((ext_vector_type(8))) short short8;   // 8 x bf16
typedef __attribute__((ext_vector_type(4))) float f32x4;

__device__ __forceinline__ float tanh_fast(float v) {
    const float e = __expf(2.0f * v);
    return 1.0f - 2.0f / (e + 1.0f);
}

// fp32 -> bf16 RNE (finite inputs)
__device__ __forceinline__ unsigned int f2bf(float f) {
    unsigned int u = __float_as_uint(f);
    return (u + 0x7fffu + ((u >> 16) & 1u)) >> 16;
}

__device__ __forceinline__ short8 cvt8(float4 lo, float4 hi) {
    short8 r;
    r[0] = (short)f2bf(lo.x); r[1] = (short)f2bf(lo.y);
    r[2] = (short)f2bf(lo.z); r[3] = (short)f2bf(lo.w);
    r[4] = (short)f2bf(hi.x); r[5] = (short)f2bf(hi.y);
    r[6] = (short)f2bf(hi.z); r[7] = (short)f2bf(hi.w);
    return r;
}

__device__ __forceinline__ unsigned int ld_flag(const unsigned int* p) {
    return __hip_atomic_load(p, __ATOMIC_RELAXED, __HIP_MEMORY_SCOPE_AGENT);
}
__device__ __forceinline__ void st_flag(unsigned int* p, unsigned int v) {
    __hip_atomic_store(p, v, __ATOMIC_RELAXED, __HIP_MEMORY_SCOPE_AGENT);
}
__device__ __forceinline__ void st_h(unsigned long long* p, unsigned long long v) {
    __hip_atomic_store(p, v, __ATOMIC_RELAXED, __HIP_MEMORY_SCOPE_AGENT);
}

// Persistent MFMA LSTM, round 21 = r16 (best: 2.149 ms) with a sleepless
// poll. Structure: barrier-free per-wave tags (packed 4B stride -> one poll
// iteration touches 4 cachelines), per-step VIRGIN h buffers read with plain
// cached loads (L2-shared across the XCD after first reader; lines are
// virgin so no stale-L2 hazard), operand-swapped MFMA (C: col=batch,
// row=gate*4+jc -> no lane transpose), all-lane gate transcendentals
// (tanh via 2*sigmoid(2x)-1), publish = 8B h-store -> vmcnt(0) drain ->
// 4B tag store. The drain is REQUIRED: r18/r19 proved tag-before-data
// reordering poisons consumer L2 with stale lines.
__global__ __launch_bounds__(NTH, 1)
void lstm_mfma(const float* __restrict__ x,
               const float* __restrict__ Wf, const float* __restrict__ bfp,
               const float* __restrict__ Wi, const float* __restrict__ bip,
               const float* __restrict__ Wg, const float* __restrict__ bgp,
               const float* __restrict__ Wo, const float* __restrict__ bop,
               float* __restrict__ out,
               unsigned int* __restrict__ ws_u32)
{
    const int tid = threadIdx.x;
    const int l   = tid & 63;
    const int mt  = tid >> 6;              // wave = M-tile (batches mt*16..+15)
    const int wg  = blockIdx.x;
    const int j0  = wg * 4;

    const int n    = l & 15;               // weight row (gate*4 + jc)
    const int khi  = l >> 4;               // k-group; in C: gate index
    const bool isg = (khi == 2);           // this lane's C-rows are gate 'g'

    unsigned int* const flags = ws_u32;    // packed: (mt*128 + wg) * 4B
    char* const hbase = (char*)ws_u32 + HBASE_OFF;

    // ---- load the 32 weight fragments (bf16) into VGPRs, once --------------
    const float* Wn = (n < 8) ? ((n < 4) ? Wf : Wi) : ((n < 12) ? Wg : Wo);
    const float* wrow = Wn + (size_t)(j0 + (n & 3)) * KTOT + khi * 8;
    short8 Bfr[32];
    #pragma unroll
    for (int kt = 0; kt < 32; ++kt) {
        Bfr[kt] = cvt8(*(const float4*)(wrow + kt * 32),
                       *(const float4*)(wrow + kt * 32 + 4));
    }
    const float* bptr = (khi == 0) ? bfp : (khi == 1) ? bip : (khi == 2) ? bgp : bop;
    const float4 bias4 = *(const float4*)(bptr + j0);

    // c-state: lanes l<16 hold c[b = mt*16+l][j0+q], q = 0..3
    float cst0 = 0.f, cst1 = 0.f, cst2 = 0.f, cst3 = 0.f;

    float* const hx_out = out + (size_t)SEQ * BATCH * DH;
    float* const cx_out = hx_out + (size_t)BATCH * DH;

    // producer-side h-fragment coordinates (constant over t)
    const int kth         = wg >> 3;                    // h k-tile 0..15
    const int lane_f_base = ((wg & 7) >> 1) << 4;       // hi<<4
    const int half8       = (wg & 1) * 8;               // byte offset of j-quad

    // self-poll pointers: the 128 same-mt producer tags (packed, 4 lines)
    const unsigned int* const f0p = flags + (size_t)mt * 128 + l;
    const unsigned int* const f1p = f0p + 64;
    unsigned int* const my_flag = flags + (size_t)mt * 128 + wg;

    const float* xrow_base = x + (size_t)(mt * 16 + n) * DIN + khi * 8;

    for (int t = 0; t < SEQ; ++t) {
        f32x4 acc_a = {0.f, 0.f, 0.f, 0.f};
        f32x4 acc_b = {0.f, 0.f, 0.f, 0.f};

        // ---------- phase X: x[t] contribution (dependency-free) -----------
        {
            const float* xr = xrow_base + (size_t)t * BATCH * DIN;
            #pragma unroll
            for (int kt = 0; kt < 16; kt += 2) {
                const short8 a0 = cvt8(*(const float4*)(xr + kt * 32),
                                       *(const float4*)(xr + kt * 32 + 4));
                const short8 a1 = cvt8(*(const float4*)(xr + (kt + 1) * 32),
                                       *(const float4*)(xr + (kt + 1) * 32 + 4));
                acc_a = __builtin_amdgcn_mfma_f32_16x16x32_bf16(Bfr[kt], a0, acc_a, 0, 0, 0);
                acc_b = __builtin_amdgcn_mfma_f32_16x16x32_bf16(Bfr[kt + 1], a1, acc_b, 0, 0, 0);
            }
        }

        if (t > 0) {
            // ------ per-wave wait: 128 same-mt tags >= t (busy, no sleep) --
            const unsigned int target = (unsigned int)t;
            for (;;) {
                const unsigned int fa = ld_flag(f0p);
                const unsigned int fb = ld_flag(f1p);
                if (__all(fa >= target && fb >= target)) break;
            }
            asm volatile("" ::: "memory");   // keep h-loads after the poll

            // ---------- phase H: h[t-1], virgin buffer, cached loads -------
            const uint4* hp = (const uint4*)(hbase + (size_t)(t - 1) * HBUF_BYTES)
                              + ((size_t)(mt * 16) * 64 + l);
            uint4 hv[16];
            #pragma unroll
            for (int kt = 0; kt < 16; ++kt) hv[kt] = hp[kt * 64];
            #pragma unroll
            for (int kt = 0; kt < 16; kt += 2) {
                union { uint4 u; short8 v; } U0, U1;
                U0.u = hv[kt]; U1.u = hv[kt + 1];
                acc_a = __builtin_amdgcn_mfma_f32_16x16x32_bf16(Bfr[16 + kt], U0.v,
                                                                acc_a, 0, 0, 0);
                acc_b = __builtin_amdgcn_mfma_f32_16x16x32_bf16(Bfr[17 + kt], U1.v,
                                                                acc_b, 0, 0, 0);
            }
        }

        // ---------- epilogue: gates on ALL lanes, gather, update -----------
        // C (swapped): col (l&15) = batch, row m = khi*4+q -> gate=khi, jc=q.
        float aq0, aq1, aq2, aq3;
        {
            const float m = isg ? 2.0f : 1.0f;
            const float p0 = acc_a[0] + acc_b[0] + bias4.x;
            const float p1 = acc_a[1] + acc_b[1] + bias4.y;
            const float p2 = acc_a[2] + acc_b[2] + bias4.z;
            const float p3 = acc_a[3] + acc_b[3] + bias4.w;
            const float y0 = 1.0f / (1.0f + __expf(-m * p0));
            const float y1 = 1.0f / (1.0f + __expf(-m * p1));
            const float y2 = 1.0f / (1.0f + __expf(-m * p2));
            const float y3 = 1.0f / (1.0f + __expf(-m * p3));
            aq0 = isg ? 2.0f * y0 - 1.0f : y0;
            aq1 = isg ? 2.0f * y1 - 1.0f : y1;
            aq2 = isg ? 2.0f * y2 - 1.0f : y2;
            aq3 = isg ? 2.0f * y3 - 1.0f : y3;
        }
        const float i0 = __shfl_xor(aq0, 16), g0 = __shfl_xor(aq0, 32), o0 = __shfl_xor(aq0, 48);
        const float i1 = __shfl_xor(aq1, 16), g1 = __shfl_xor(aq1, 32), o1 = __shfl_xor(aq1, 48);
        const float i2 = __shfl_xor(aq2, 16), g2 = __shfl_xor(aq2, 32), o2 = __shfl_xor(aq2, 48);
        const float i3 = __shfl_xor(aq3, 16), g3 = __shfl_xor(aq3, 32), o3 = __shfl_xor(aq3, 48);

        const bool active = (l < 16);            // lane l = batch mt*16+l
        float hq0 = 0.f, hq1 = 0.f, hq2 = 0.f, hq3 = 0.f;

        if (active) {
            cst0 = fmaf(aq0, cst0, i0 * g0); hq0 = o0 * tanh_fast(cst0);
            cst1 = fmaf(aq1, cst1, i1 * g1); hq1 = o1 * tanh_fast(cst1);
            cst2 = fmaf(aq2, cst2, i2 * g2); hq2 = o2 * tanh_fast(cst2);
            cst3 = fmaf(aq3, cst3, i3 * g3); hq3 = o3 * tanh_fast(cst3);

            if (t < SEQ - 1) {
                // direct 8B h-pack: this lane's 4 jc-values of batch mt*16+l
                const unsigned long long pk =
                    (unsigned long long)(f2bf(hq0) | (f2bf(hq1) << 16))
                    | ((unsigned long long)(f2bf(hq2) | (f2bf(hq3) << 16)) << 32);
                char* const wb = hbase + (size_t)t * HBUF_BYTES;
                unsigned long long* hp_w = (unsigned long long*)
                    (wb + (((size_t)(mt * 16 + kth) * 64
                            + (lane_f_base | l)) << 4) + half8);
                st_h(hp_w, pk);     // sc1 write-through: visible at IF$
            }
        }

        if (t < SEQ - 1) {
            // this wave's h-stores drained, then publish this wave's tag.
            // (drain REQUIRED: r18/r19 showed tag-before-data poisons L2)
            asm volatile("s_waitcnt vmcnt(0)" ::: "memory");
            if (l == 0) st_flag(my_flag, (unsigned int)(t + 1));
        }

        if (active) {      // out writes off the critical path
            const int b = mt * 16 + l;
            const float4 ov = make_float4(hq0, hq1, hq2, hq3);
            *(float4*)(out + ((size_t)t * BATCH + b) * DH + j0) = ov;
            if (t == SEQ - 1) {
                *(float4*)(hx_out + (size_t)b * DH + j0) = ov;
                *(float4*)(cx_out + (size_t)b * DH + j0) =
                    make_float4(cst0, cst1, cst2, cst3);
            }
        }
    }
}

extern "C" void kernel_launch(void* const* d_in, const int* in_sizes, int n_in,
                              void* d_out, int out_size, void* d_ws, size_t ws_size,
                              hipStream_t stream)
{
    const float* x  = (const float*)d_in[0];
    const float* Wf = (const float*)d_in[1];
    const float* bf = (const float*)d_in[2];
    const float* Wi = (const float*)d_in[3];
    const float* bi = (const float*)d_in[4];
    const float* Wg = (const float*)d_in[5];
    const float* bg = (const float*)d_in[6];
    const float* Wo = (const float*)d_in[7];
    const float* bo = (const float*)d_in[8];
    float* out = (float*)d_out;

    // Tags must be 0 every call (monotone within a call; ws poisoned 0xAA
    // once, never re-poisoned). h buffers: virgin per step, written before
    // read (tag-gated); across graph replays values are byte-identical.
    (void)hipMemsetAsync(d_ws, 0, FLAGS_BYTES, stream);

    lstm_mfma<<<NWG, NTH, 0, stream>>>(x, Wf, bf, Wi, bi, Wg, bg, Wo, bo,
                                       out, (unsigned int*)d_ws);
}

// Round 22
// 2157.513 us; speedup vs baseline: 1.9095x; 1.4326x over previous
//
#include <hip/hip_runtime.h>

#define SEQ   512
#define BATCH 64
#define DIN   512
#define DH    512
#define KTOT  1024
#define NWG   128
#define NTH   256
#define HBUF_BYTES 65536   // one h step: 64 tiles * 64 lanes * 16 B

// ws layout (bytes):
//   [0, 2K)            PACKED per-(mt,wg) tags: (mt*128 + wg) * 4B
//                      (poll sweep touches 4 lines, not 128)
//   [64K, ...)         MODE0: ping-pong h (2 x 64 KB)
//                      MODE1/2: per-step virgin h buffers (511 x 64 KB)
//   [33M, 33M+32M)     MODE2: x pre-converted to bf16 fragment layout
#define FLAGS_BYTES 65536
#define HBASE_OFF   65536
#define XBF_OFF     (HBASE_OFF + 512 * HBUF_BYTES)        // ~33.6 MB
#define XBF_BYTES   ((size_t)SEQ * 4 * 16 * 1024)         // 32 MB
#define WS_MODE1    ((size_t)HBASE_OFF + 511 * HBUF_BYTES)
#define WS_MODE2    ((size_t)XBF_OFF + XBF_BYTES)
#define FLAG_STRIDE 1    // uints (4 B) — packed

typedef __attribute__((ext_vector_type(8))) short short8;   // 8 x bf16
typedef __attribute__((ext_vector_type(4))) float f32x4;

__device__ __forceinline__ float tanh_fast(float v) {
    const float e = __expf(2.0f * v);
    return 1.0f - 2.0f / (e + 1.0f);
}

// fp32 -> bf16 RNE (finite inputs)
__device__ __forceinline__ unsigned int f2bf(float f) {
    unsigned int u = __float_as_uint(f);
    return (u + 0x7fffu + ((u >> 16) & 1u)) >> 16;
}

__device__ __forceinline__ short8 cvt8(float4 lo, float4 hi) {
    short8 r;
    r[0] = (short)f2bf(lo.x); r[1] = (short)f2bf(lo.y);
    r[2] = (short)f2bf(lo.z); r[3] = (short)f2bf(lo.w);
    r[4] = (short)f2bf(hi.x); r[5] = (short)f2bf(hi.y);
    r[6] = (short)f2bf(hi.z); r[7] = (short)f2bf(hi.w);
    return r;
}

__device__ __forceinline__ unsigned int ld_flag(const unsigned int* p) {
    return __hip_atomic_load(p, __ATOMIC_RELAXED, __HIP_MEMORY_SCOPE_AGENT);
}
__device__ __forceinline__ void st_flag(unsigned int* p, unsigned int v) {
    __hip_atomic_store(p, v, __ATOMIC_RELAXED, __HIP_MEMORY_SCOPE_AGENT);
}
__device__ __forceinline__ unsigned long long ld_h_sc1(const unsigned long long* p) {
    return __hip_atomic_load(p, __ATOMIC_RELAXED, __HIP_MEMORY_SCOPE_AGENT);
}
__device__ __forceinline__ void st_h(unsigned long long* p, unsigned long long v) {
    __hip_atomic_store(p, v, __ATOMIC_RELAXED, __HIP_MEMORY_SCOPE_AGENT);
}

// Pre-pass: x fp32 -> bf16 in MFMA fragment layout.
// idx = ((t*4 + mt)*16 + kt)*64 + l holds x[t][mt*16+(l&15)][kt*32+(l>>4)*8 ..+8]
__global__ __launch_bounds__(256)
void xconv(const float* __restrict__ x, unsigned short* __restrict__ xbf)
{
    const int gid = blockIdx.x * 256 + threadIdx.x;
    const int l   = gid & 63;
    const int kt  = (gid >> 6) & 15;
    const int mtt = (gid >> 10) & 3;
    const int t   = gid >> 12;
    const float* src = x + ((size_t)t * BATCH + mtt * 16 + (l & 15)) * DIN
                         + kt * 32 + (l >> 4) * 8;
    *(short8*)(xbf + (size_t)gid * 8) =
        cvt8(*(const float4*)src, *(const float4*)(src + 4));
}

// Persistent MFMA LSTM — FINAL (= round 16, best measured: 2.149 ms).
// Structure and the experimental evidence behind each piece:
//  * barrier-free per-wave tags, sc1, PACKED at 4B stride (r12: beats
//    WG-barriers/delegation; r16: packing cut poll line-traffic 32x, -3%)
//  * publish = 8B h-store -> vmcnt(0) drain -> tag store (drain REQUIRED:
//    r18/r19 showed tag-before-data poisons consumer L2 with stale lines;
//    r20 showed coalescing the store hurts the consumer load pattern)
//  * per-step VIRGIN h buffers, plain cached consumer loads (r8: +32%,
//    L2-shared broadcast on each XCD; virgin lines = no stale-L2 hazard)
//  * poll throttled by s_sleep(1) (r21: sleepless poll floods fabric, -44%)
//  * operand-swapped MFMA mfma(W, act): C col=batch, row=gate*4+jc ->
//    no lane transpose, float4 epilogue stores (r10)
//  * all-lane gate transcendentals via tanh(x)=2*sigmoid(2x)-1 (r9)
// MODE 0: ping-pong h, sc1 loads  / MODE 1: virgin buffers, cached loads /
// MODE 2: MODE1 + pre-converted bf16 x.
template <int MODE>
__global__ __launch_bounds__(NTH, 1)
void lstm_mfma(const float* __restrict__ x,
               const unsigned short* __restrict__ xbf,
               const float* __restrict__ Wf, const float* __restrict__ bfp,
               const float* __restrict__ Wi, const float* __restrict__ bip,
               const float* __restrict__ Wg, const float* __restrict__ bgp,
               const float* __restrict__ Wo, const float* __restrict__ bop,
               float* __restrict__ out,
               unsigned int* __restrict__ ws_u32)
{
    const int tid = threadIdx.x;
    const int l   = tid & 63;
    const int mt  = tid >> 6;              // wave = M-tile (batches mt*16..+15)
    const int wg  = blockIdx.x;
    const int j0  = wg * 4;

    const int n    = l & 15;               // weight row (gate*4 + jc)
    const int khi  = l >> 4;               // k-group; in C: gate index
    const bool isg = (khi == 2);           // this lane's C-rows are gate 'g'

    unsigned int* const flags = ws_u32;    // (mt*128 + wg) * FLAG_STRIDE
    char* const hbase = (char*)ws_u32 + HBASE_OFF;

    // ---- load the 32 weight fragments (bf16) into VGPRs, once --------------
    const float* Wn = (n < 8) ? ((n < 4) ? Wf : Wi) : ((n < 12) ? Wg : Wo);
    const float* wrow = Wn + (size_t)(j0 + (n & 3)) * KTOT + khi * 8;
    short8 Bfr[32];
    #pragma unroll
    for (int kt = 0; kt < 32; ++kt) {
        Bfr[kt] = cvt8(*(const float4*)(wrow + kt * 32),
                       *(const float4*)(wrow + kt * 32 + 4));
    }
    // bias: this lane's C-gate (khi) at columns j0..j0+3
    const float* bptr = (khi == 0) ? bfp : (khi == 1) ? bip : (khi == 2) ? bgp : bop;
    const float4 bias4 = *(const float4*)(bptr + j0);

    // c-state: lanes l<16 hold c[b = mt*16+l][j0+q], q = 0..3
    float cst0 = 0.f, cst1 = 0.f, cst2 = 0.f, cst3 = 0.f;

    float* const hx_out = out + (size_t)SEQ * BATCH * DH;
    float* const cx_out = hx_out + (size_t)BATCH * DH;

    // producer-side h-fragment coordinates (constant over t)
    const int kth         = wg >> 3;                    // h k-tile 0..15
    const int lane_f_base = ((wg & 7) >> 1) << 4;       // hi<<4
    const int half8       = (wg & 1) * 8;               // byte offset of j-quad

    // self-poll pointers: the 128 same-mt producer tags (packed, 4 lines)
    const unsigned int* const f0p = flags + ((size_t)mt * 128 + l) * FLAG_STRIDE;
    const unsigned int* const f1p = f0p + (size_t)64 * FLAG_STRIDE;
    unsigned int* const my_flag = flags + ((size_t)mt * 128 + wg) * FLAG_STRIDE;

    const float*  xrow_base = x + (size_t)(mt * 16 + (l & 15)) * DIN + khi * 8;
    const short8* xbf_base  = (const short8*)xbf + (size_t)mt * 16 * 64 + l;

    for (int t = 0; t < SEQ; ++t) {
        f32x4 acc_a = {0.f, 0.f, 0.f, 0.f};
        f32x4 acc_b = {0.f, 0.f, 0.f, 0.f};

        // ---------- phase X: x[t] contribution (dependency-free) -----------
        if (MODE == 2) {
            const short8* xp = xbf_base + (size_t)t * 4096;   // (t*4+mt)*16*64+l
            #pragma unroll
            for (int kt = 0; kt < 16; kt += 2) {
                acc_a = __builtin_amdgcn_mfma_f32_16x16x32_bf16(Bfr[kt], xp[kt * 64],
                                                                acc_a, 0, 0, 0);
                acc_b = __builtin_amdgcn_mfma_f32_16x16x32_bf16(Bfr[kt + 1], xp[(kt + 1) * 64],
                                                                acc_b, 0, 0, 0);
            }
        } else {
            const float* xr = xrow_base + (size_t)t * BATCH * DIN;
            #pragma unroll
            for (int kt = 0; kt < 16; kt += 2) {
                const short8 a0 = cvt8(*(const float4*)(xr + kt * 32),
                                       *(const float4*)(xr + kt * 32 + 4));
                const short8 a1 = cvt8(*(const float4*)(xr + (kt + 1) * 32),
                                       *(const float4*)(xr + (kt + 1) * 32 + 4));
                acc_a = __builtin_amdgcn_mfma_f32_16x16x32_bf16(Bfr[kt], a0, acc_a, 0, 0, 0);
                acc_b = __builtin_amdgcn_mfma_f32_16x16x32_bf16(Bfr[kt + 1], a1, acc_b, 0, 0, 0);
            }
        }

        if (t > 0) {
            // ------ per-wave dependency wait: 128 same-mt tags >= t --------
            const unsigned int target = (unsigned int)t;
            for (;;) {
                const unsigned int fa = ld_flag(f0p);
                const unsigned int fb = ld_flag(f1p);
                if (__all(fa >= target && fb >= target)) break;
                __builtin_amdgcn_s_sleep(1);
            }
            asm volatile("" ::: "memory");   // keep h-loads after the poll

            // ---------- phase H: h[t-1] -------------------------------------
            if (MODE == 0) {
                const unsigned long long* hp =
                    (const unsigned long long*)(hbase + ((t & 1) ^ 1) * HBUF_BYTES)
                    + ((size_t)(mt * 16) * 64 + l) * 2;
                #pragma unroll
                for (int kt = 0; kt < 16; kt += 2) {
                    union { unsigned long long u[2]; short8 v; } U0, U1;
                    U0.u[0] = ld_h_sc1(hp + kt * 128);
                    U0.u[1] = ld_h_sc1(hp + kt * 128 + 1);
                    U1.u[0] = ld_h_sc1(hp + (kt + 1) * 128);
                    U1.u[1] = ld_h_sc1(hp + (kt + 1) * 128 + 1);
                    acc_a = __builtin_amdgcn_mfma_f32_16x16x32_bf16(Bfr[16 + kt], U0.v,
                                                                    acc_a, 0, 0, 0);
                    acc_b = __builtin_amdgcn_mfma_f32_16x16x32_bf16(Bfr[17 + kt], U1.v,
                                                                    acc_b, 0, 0, 0);
                }
            } else {
                // virgin per-step buffer: plain CACHED loads (L2-shared/XCD)
                const uint4* hp = (const uint4*)(hbase + (size_t)(t - 1) * HBUF_BYTES)
                                  + ((size_t)(mt * 16) * 64 + l);
                uint4 hv[16];
                #pragma unroll
                for (int kt = 0; kt < 16; ++kt) hv[kt] = hp[kt * 64];
                #pragma unroll
                for (int kt = 0; kt < 16; kt += 2) {
                    union { uint4 u; short8 v; } U0, U1;
                    U0.u = hv[kt]; U1.u = hv[kt + 1];
                    acc_a = __builtin_amdgcn_mfma_f32_16x16x32_bf16(Bfr[16 + kt], U0.v,
                                                                    acc_a, 0, 0, 0);
                    acc_b = __builtin_amdgcn_mfma_f32_16x16x32_bf16(Bfr[17 + kt], U1.v,
                                                                    acc_b, 0, 0, 0);
                }
            }
        }

        // ---------- epilogue: gates on ALL lanes, gather, update -----------
        // C (swapped): col (l&15) = batch, row m = khi*4+q -> gate=khi, jc=q.
        float aq0, aq1, aq2, aq3;
        {
            const float m = isg ? 2.0f : 1.0f;
            const float p0 = acc_a[0] + acc_b[0] + bias4.x;
            const float p1 = acc_a[1] + acc_b[1] + bias4.y;
            const float p2 = acc_a[2] + acc_b[2] + bias4.z;
            const float p3 = acc_a[3] + acc_b[3] + bias4.w;
            const float y0 = 1.0f / (1.0f + __expf(-m * p0));
            const float y1 = 1.0f / (1.0f + __expf(-m * p1));
            const float y2 = 1.0f / (1.0f + __expf(-m * p2));
            const float y3 = 1.0f / (1.0f + __expf(-m * p3));
            aq0 = isg ? 2.0f * y0 - 1.0f : y0;
            aq1 = isg ? 2.0f * y1 - 1.0f : y1;
            aq2 = isg ? 2.0f * y2 - 1.0f : y2;
            aq3 = isg ? 2.0f * y3 - 1.0f : y3;
        }
        const float i0 = __shfl_xor(aq0, 16), g0 = __shfl_xor(aq0, 32), o0 = __shfl_xor(aq0, 48);
        const float i1 = __shfl_xor(aq1, 16), g1 = __shfl_xor(aq1, 32), o1 = __shfl_xor(aq1, 48);
        const float i2 = __shfl_xor(aq2, 16), g2 = __shfl_xor(aq2, 32), o2 = __shfl_xor(aq2, 48);
        const float i3 = __shfl_xor(aq3, 16), g3 = __shfl_xor(aq3, 32), o3 = __shfl_xor(aq3, 48);

        const bool active = (l < 16);            // lane l = batch mt*16+l
        float hq0 = 0.f, hq1 = 0.f, hq2 = 0.f, hq3 = 0.f;

        if (active) {
            cst0 = fmaf(aq0, cst0, i0 * g0); hq0 = o0 * tanh_fast(cst0);
            cst1 = fmaf(aq1, cst1, i1 * g1); hq1 = o1 * tanh_fast(cst1);
            cst2 = fmaf(aq2, cst2, i2 * g2); hq2 = o2 * tanh_fast(cst2);
            cst3 = fmaf(aq3, cst3, i3 * g3); hq3 = o3 * tanh_fast(cst3);

            if (t < SEQ - 1) {
                // direct 8B h-pack: this lane's 4 jc-values of batch mt*16+l
                const unsigned long long pk =
                    (unsigned long long)(f2bf(hq0) | (f2bf(hq1) << 16))
                    | ((unsigned long long)(f2bf(hq2) | (f2bf(hq3) << 16)) << 32);
                char* const wb = (MODE == 0) ? hbase + (t & 1) * HBUF_BYTES
                                             : hbase + (size_t)t * HBUF_BYTES;
                unsigned long long* hp_w = (unsigned long long*)
                    (wb + (((size_t)(mt * 16 + kth) * 64
                            + (lane_f_base | l)) << 4) + half8);
                st_h(hp_w, pk);     // sc1 write-through: visible at IF$
            }
        }

        if (t < SEQ - 1) {
            // this wave's h-stores drained, then publish this wave's tag
            asm volatile("s_waitcnt vmcnt(0)" ::: "memory");
            if (l == 0) st_flag(my_flag, (unsigned int)(t + 1));
        }

        if (active) {      // out writes off the critical path
            const int b = mt * 16 + l;
            const float4 ov = make_float4(hq0, hq1, hq2, hq3);
            *(float4*)(out + ((size_t)t * BATCH + b) * DH + j0) = ov;
            if (t == SEQ - 1) {
                *(float4*)(hx_out + (size_t)b * DH + j0) = ov;
                *(float4*)(cx_out + (size_t)b * DH + j0) =
                    make_float4(cst0, cst1, cst2, cst3);
            }
        }
    }
}

extern "C" void kernel_launch(void* const* d_in, const int* in_sizes, int n_in,
                              void* d_out, int out_size, void* d_ws, size_t ws_size,
                              hipStream_t stream)
{
    const float* x  = (const float*)d_in[0];
    const float* Wf = (const float*)d_in[1];
    const float* bf = (const float*)d_in[2];
    const float* Wi = (const float*)d_in[3];
    const float* bi = (const float*)d_in[4];
    const float* Wg = (const float*)d_in[5];
    const float* bg = (const float*)d_in[6];
    const float* Wo = (const float*)d_in[7];
    const float* bo = (const float*)d_in[8];
    float* out = (float*)d_out;

    // Tag flags must be 0 every call (monotone within a call; ws poisoned 0xAA
    // once, never re-poisoned). h buffers: written-before-read each call;
    // across graph replays values are identical, so cached copies stay valid.
    (void)hipMemsetAsync(d_ws, 0, FLAGS_BYTES, stream);

    unsigned int* wsp = (unsigned int*)d_ws;
    if (ws_size >= WS_MODE2) {
        unsigned short* xbf = (unsigned short*)((char*)d_ws + XBF_OFF);
        xconv<<<SEQ * 4 * 16 * 64 / 256, 256, 0, stream>>>(x, xbf);
        lstm_mfma<2><<<NWG, NTH, 0, stream>>>(x, xbf, Wf, bf, Wi, bi,
                                              Wg, bg, Wo, bo, out, wsp);
    } else if (ws_size >= WS_MODE1) {
        lstm_mfma<1><<<NWG, NTH, 0, stream>>>(x, nullptr, Wf, bf, Wi, bi,
                                              Wg, bg, Wo, bo, out, wsp);
    } else {
        lstm_mfma<0><<<NWG, NTH, 0, stream>>>(x, nullptr, Wf, bf, Wi, bi,
                                              Wg, bg, Wo, bo, out, wsp);
    }
}